// Round 7
// baseline (3347.969 us; speedup 1.0000x reference)
//
#include <hip/hip_runtime.h>
#include <stdint.h>

// Problem dims (fixed): T=256, B=128, I=512, H=1024, O=1
typedef __attribute__((ext_vector_type(8))) short short8;
typedef __attribute__((ext_vector_type(4))) float f32x4;
typedef __attribute__((ext_vector_type(4))) unsigned int u32x4;

__device__ __forceinline__ unsigned short f2bf(float f) {
  unsigned u = __float_as_uint(f);
  u += 0x7FFFu + ((u >> 16) & 1u);   // RNE
  return (unsigned short)(u >> 16);
}
__device__ __forceinline__ float bf2f(unsigned short s) {
  return __uint_as_float(((unsigned)s) << 16);
}
__device__ __forceinline__ float ftanh(float x) {
  float e = __expf(2.0f * x);
  return 1.0f - 2.0f / (e + 1.0f);
}

// ---------------- fp32 -> bf16 convert (vectorized, 8 elem/thread) ----------
__global__ __launch_bounds__(256) void cvt_kernel(const float* __restrict__ in,
                                                  unsigned short* __restrict__ out,
                                                  int n8) {
  int i = blockIdx.x * 256 + threadIdx.x;
  if (i >= n8) return;
  const float4* p = (const float4*)in + (size_t)i * 2;
  float4 a = p[0], b = p[1];
  uint4 o;
  o.x = (unsigned)f2bf(a.x) | ((unsigned)f2bf(a.y) << 16);
  o.y = (unsigned)f2bf(a.z) | ((unsigned)f2bf(a.w) << 16);
  o.z = (unsigned)f2bf(b.x) | ((unsigned)f2bf(b.y) << 16);
  o.w = (unsigned)f2bf(b.z) | ((unsigned)f2bf(b.w) << 16);
  ((uint4*)out)[i] = o;
}

// ---------------- xp GEMM: xp[m][n] = sum_k x[m][k]*W_ih[n][k] + b_ih[n]+b_hh[n]
__global__ __launch_bounds__(256) void gemm_xp(const unsigned short* __restrict__ A,
                                               const unsigned short* __restrict__ Bw,
                                               const float* __restrict__ b_ih,
                                               const float* __restrict__ b_hh,
                                               unsigned short* __restrict__ xp) {
  __shared__ unsigned short Al[8192];
  __shared__ unsigned short Bl[8192];
  int tid = threadIdx.x, lane = tid & 63, w = tid >> 6;
  int wm = w & 1, wn = w >> 1;
  int bx = blockIdx.x;
  int m0 = (bx >> 3) * 128, n0 = (bx & 7) * 128;

  f32x4 acc[4][4];
#pragma unroll
  for (int i = 0; i < 4; ++i)
#pragma unroll
    for (int jq = 0; jq < 4; ++jq) acc[i][jq] = (f32x4){0.f, 0.f, 0.f, 0.f};

  for (int kb = 0; kb < 512; kb += 64) {
#pragma unroll
    for (int i = 0; i < 4; ++i) {
      int S = (w * 4 + i) * 64 + lane;
      int row = S >> 3, pg = S & 7;
      int gk = ((pg ^ (row & 7)) << 3);
      const unsigned short* ga = A + (size_t)(m0 + row) * 512 + kb + gk;
      const unsigned short* gb = Bw + (size_t)(n0 + row) * 512 + kb + gk;
      __builtin_amdgcn_global_load_lds(
          (const __attribute__((address_space(1))) unsigned int*)ga,
          (__attribute__((address_space(3))) unsigned int*)&Al[(size_t)((w * 4 + i) * 64) * 8],
          16, 0, 0);
      __builtin_amdgcn_global_load_lds(
          (const __attribute__((address_space(1))) unsigned int*)gb,
          (__attribute__((address_space(3))) unsigned int*)&Bl[(size_t)((w * 4 + i) * 64) * 8],
          16, 0, 0);
    }
    asm volatile("s_waitcnt vmcnt(0)" ::: "memory");
    __syncthreads();

#pragma unroll
    for (int c = 0; c < 2; ++c) {
      short8 av[4], bv[4];
      int gg = c * 4 + (lane >> 4);
#pragma unroll
      for (int mt = 0; mt < 4; ++mt) {
        int rowa = wm * 64 + mt * 16 + (lane & 15);
        av[mt] = *(const short8*)&Al[(rowa * 8 + (gg ^ (rowa & 7))) * 8];
        int rowb = wn * 64 + mt * 16 + (lane & 15);
        bv[mt] = *(const short8*)&Bl[(rowb * 8 + (gg ^ (rowb & 7))) * 8];
      }
#pragma unroll
      for (int mt = 0; mt < 4; ++mt)
#pragma unroll
        for (int nt = 0; nt < 4; ++nt)
          acc[mt][nt] = __builtin_amdgcn_mfma_f32_16x16x32_bf16(av[mt], bv[nt], acc[mt][nt], 0, 0, 0);
    }
    __syncthreads();
  }

  int cl = lane & 15, qd = lane >> 4;
#pragma unroll
  for (int nt = 0; nt < 4; ++nt) {
    int col = n0 + wn * 64 + nt * 16 + cl;
    float bias = b_ih[col] + b_hh[col];
#pragma unroll
    for (int mt = 0; mt < 4; ++mt) {
#pragma unroll
      for (int r = 0; r < 4; ++r) {
        int m = m0 + wm * 64 + mt * 16 + qd * 4 + r;
        xp[(size_t)m * 1024 + col] = f2bf(acc[mt][nt][r] + bias);
      }
    }
  }
}

// ---- one bulk pass: 16 chunks (8 tagged dwords each) -> packed A-frags.
// Returns AND over all 128 dwords. BYP: bypass caches (retry path).
template <bool BYP>
__device__ __forceinline__ unsigned pass16(const unsigned* __restrict__ slotr,
                                           int c0, short8* av) {
  u32x4 A[16], B[16];
#pragma unroll
  for (int i = 0; i < 16; ++i) {
    const unsigned* pa = slotr + (size_t)(c0 + i) * 32;
    if (BYP) {
      asm volatile("global_load_dwordx4 %0, %1, off sc0 sc1"
                   : "=v"(A[i]) : "v"((unsigned long long)(uintptr_t)pa) : "memory");
      asm volatile("global_load_dwordx4 %0, %1, off sc0 sc1"
                   : "=v"(B[i]) : "v"((unsigned long long)(uintptr_t)(pa + 4)) : "memory");
    } else {
      A[i] = *(const u32x4*)pa;
      B[i] = *(const u32x4*)(pa + 4);
    }
  }
  if (BYP) asm volatile("s_waitcnt vmcnt(0)" ::: "memory");
  unsigned aa = 0xFFFFFFFFu;
#pragma unroll
  for (int i = 0; i < 16; ++i) {
    u32x4 a = A[i], b = B[i];
    u32x4 nd = a & b;
    aa &= nd.x & nd.y & nd.z & nd.w;
    short8 sv;
    sv[0] = (short)a.x; sv[1] = (short)a.y; sv[2] = (short)a.z; sv[3] = (short)a.w;
    sv[4] = (short)b.x; sv[5] = (short)b.y; sv[6] = (short)b.z; sv[7] = (short)b.w;
    av[c0 + i] = sv;
  }
  return aa;
}

// ---------------- the scan (one-way tagged publish, no acks) ----------------
// 128 WGs x 256 thr (4 waves), 1 WG/CU. group g = blk&7 (16 batches),
// producer p = blk>>3, wave w owns cols p*64+w*16..+16. Per step:
// (a) poll 64 fire-and-forget sentinel words (4 B/lane, exact ==s-1);
// (b) PLAIN bulk-load the tagged h[s-1] slot (ring-64: per-step-unique
//     addresses -> cache-fresh; group's WGs share XCD L2 fills);
// (c) verify: AND over all tag halves == s-1 (ring pre-zeroed: unwritten=0,
//     stale=s-65, poison impossible; 4-B stores are atomic) -> rare
//     sc0 sc1 reload loop on failure;
// (d) MFMA (W_hh B-frags register-resident), tanh;
// (e) publish h[s] as (s<<16)|bf16 dwords, fire-and-forget sc0 sc1 (NO
//     vmcnt ack -- the tag rides with the data), then sentinel word.
// Head partials -> private pscratch slots; trailing reduce kernel. No
// barriers, no LDS, no atomics anywhere in the loop.
__global__ __launch_bounds__(256, 1) void scan_kernel(
    const float* __restrict__ Whh, const unsigned short* __restrict__ xp,
    const float* __restrict__ Wfc, unsigned* __restrict__ ring,
    unsigned* __restrict__ tags, float* __restrict__ pscratch) {
  const int tid = threadIdx.x;
  const int lane = tid & 63, w = tid >> 6;
  const int g = blockIdx.x & 7, p = blockIdx.x >> 3;
  const int r = lane & 15, q = lane >> 4;
  const int b0 = g * 16;
  const int gcol = p * 64 + w * 16 + r;
  const int myid = p * 4 + w;
  const float wfcv = Wfc[gcol];

  // ---- W_hh -> register B-frags: lane (r,q) holds W[gcol][c*32+q*8..+7]
  short8 Bfrag[32];
  {
    const float* wsrc = Whh + (size_t)gcol * 1024 + q * 8;
#pragma unroll
    for (int c = 0; c < 32; ++c) {
      float4 v0 = *(const float4*)(wsrc + c * 32);
      float4 v1 = *(const float4*)(wsrc + c * 32 + 4);
      short8 sv;
      sv[0] = (short)f2bf(v0.x); sv[1] = (short)f2bf(v0.y);
      sv[2] = (short)f2bf(v0.z); sv[3] = (short)f2bf(v0.w);
      sv[4] = (short)f2bf(v1.x); sv[5] = (short)f2bf(v1.y);
      sv[6] = (short)f2bf(v1.z); sv[7] = (short)f2bf(v1.w);
      Bfrag[c] = sv;
    }
  }

  short8 av[32];
  float xpv[4];

  for (int s = 1; s < 256; ++s) {
    if (s == 1) {
      // ---- h0 computed locally (no publish, no sync)
#pragma unroll
      for (int c = 0; c < 32; ++c) {
        u32x4 xv = *(const u32x4*)(xp + (size_t)(b0 + r) * 1024 + c * 32 + q * 8);
        const unsigned short* xs = (const unsigned short*)&xv;
        short8 sv;
#pragma unroll
        for (int j = 0; j < 8; ++j) sv[j] = (short)f2bf(ftanh(bf2f(xs[j])));
        av[c] = sv;
      }
      // head t=0: one wave per group computes it; everyone zero-fills slots
      float pp = 0.f;
      if (p == 0 && w == 0) {
#pragma unroll
        for (int c = 0; c < 32; ++c)
#pragma unroll
          for (int j = 0; j < 8; ++j)
            pp += bf2f((unsigned short)av[c][j]) * Wfc[c * 32 + q * 8 + j];
      }
      pp += __shfl_xor(pp, 16, 64);
      pp += __shfl_xor(pp, 32, 64);
      if (lane < 16)
        pscratch[(size_t)(b0 + lane) * 64 + myid] = (p == 0 && w == 0) ? pp : 0.f;
#pragma unroll
      for (int rr = 0; rr < 4; ++rr)
        xpv[rr] = bf2f(xp[((size_t)128 + b0 + q * 4 + rr) * 1024 + gcol]);
    } else {
      const unsigned T = (unsigned)(s - 1);
      // ---- (a) sentinel poll: lane l checks producer-wave l
      {
        const unsigned* ta = tags + (size_t)(((s - 1) & 3) * 512) + g * 64 + lane;
        int guard = 0;
        while (true) {
          unsigned tv;
          asm volatile("global_load_dword %0, %1, off sc0 sc1\n\ts_waitcnt vmcnt(0)"
                       : "=v"(tv)
                       : "v"((unsigned long long)(uintptr_t)ta)
                       : "memory");
          if (__all(tv == T)) break;
          if (++guard > (1 << 20)) break;  // fail-safe: terminate (fails check)
        }
      }
      // xp for this step (hidden under bulk+MFMA)
#pragma unroll
      for (int rr = 0; rr < 4; ++rr)
        xpv[rr] = bf2f(xp[((size_t)s * 128 + b0 + q * 4 + rr) * 1024 + gcol]);

      // ---- (b)+(c) plain bulk load + AND-verify
      const unsigned* slotr = ring + (size_t)((s - 1) & 63) * 131072 +
                              (size_t)(b0 + r) * 1024 + q * 8;
      unsigned aa = pass16<false>(slotr, 0, av) & pass16<false>(slotr, 16, av);
      if ((aa >> 16) != T) {
        int guard2 = 0;
        do {
          aa = pass16<true>(slotr, 0, av) & pass16<true>(slotr, 16, av);
        } while ((aa >> 16) != T && ++guard2 < 8192);
      }
    }

    // ---- (d) MFMA: 16x16 tile over K=1024, 4 independent chains
    f32x4 acc[4];
#pragma unroll
    for (int i = 0; i < 4; ++i) acc[i] = (f32x4){0.f, 0.f, 0.f, 0.f};
#pragma unroll
    for (int c = 0; c < 32; ++c)
      acc[c & 3] = __builtin_amdgcn_mfma_f32_16x16x32_bf16(av[c], Bfrag[c], acc[c & 3], 0, 0, 0);

    // ---- (e) tanh + one-way tagged publish (fire-and-forget)
    unsigned* slotw = ring + (size_t)(s & 63) * 131072;
    const unsigned tw = (unsigned)s << 16;
    float hv4[4];
#pragma unroll
    for (int rr = 0; rr < 4; ++rr) {
      float h = ftanh(acc[0][rr] + acc[1][rr] + acc[2][rr] + acc[3][rr] + xpv[rr]);
      hv4[rr] = h;
      unsigned word = tw | (unsigned)f2bf(h);
      unsigned* pa = slotw + (size_t)(b0 + q * 4 + rr) * 1024 + gcol;
      asm volatile("global_store_dword %0, %1, off sc0 sc1"
                   :: "v"((unsigned long long)(uintptr_t)pa), "v"(word) : "memory");
    }

    // ---- head partials (plain stores, contention-free)
#pragma unroll
    for (int rr = 0; rr < 4; ++rr) {
      float pp = hv4[rr] * wfcv;
      pp += __shfl_xor(pp, 1, 64);
      pp += __shfl_xor(pp, 2, 64);
      pp += __shfl_xor(pp, 4, 64);
      pp += __shfl_xor(pp, 8, 64);
      if (r == 0)
        pscratch[(size_t)(s * 128 + b0 + q * 4 + rr) * 64 + myid] = pp;
    }

    // ---- sentinel last (gives data stores a head start; verify covers races)
    if (lane == 0) {
      unsigned* ta = tags + (size_t)((s & 3) * 512) + g * 64 + myid;
      asm volatile("global_store_dword %0, %1, off sc0 sc1"
                   :: "v"((unsigned long long)(uintptr_t)ta), "v"((unsigned)s) : "memory");
    }
  }
}

// ---------------- head reduce: out[o] = sum_slot pscratch[o][slot] + bfc ----
__global__ __launch_bounds__(256) void head_reduce(const float* __restrict__ pscratch,
                                                   const float* __restrict__ bfc,
                                                   float* __restrict__ out) {
  int wid = blockIdx.x * 4 + (threadIdx.x >> 6);
  int l = threadIdx.x & 63;
  float v = pscratch[(size_t)wid * 64 + l];
#pragma unroll
  for (int off = 32; off; off >>= 1) v += __shfl_down(v, off, 64);
  if (l == 0) out[wid] = v + bfc[0];
}

// ---------------- launcher --------------------------------------------------
extern "C" void kernel_launch(void* const* d_in, const int* in_sizes, int n_in,
                              void* d_out, int out_size, void* d_ws, size_t ws_size,
                              hipStream_t stream) {
  (void)in_sizes; (void)n_in; (void)out_size; (void)ws_size;
  const float* x   = (const float*)d_in[0];
  const float* Wih = (const float*)d_in[1];
  const float* Whh = (const float*)d_in[2];
  const float* bih = (const float*)d_in[3];
  const float* bhh = (const float*)d_in[4];
  const float* Wfc = (const float*)d_in[5];
  const float* bfc = (const float*)d_in[6];
  float* out = (float*)d_out;

  char* ws = (char*)d_ws;
  // Layout (104 MB + 8 KB):
  //   xp       @0      64 MB  (bf16, live for whole scan)
  //   ring     @64M    32 MB  (64 slots x 512 KB tagged dwords; memset-0
  //                            AFTER gemm -- xb aliases it before)
  //   pscratch @96M     8 MB  (head partials; fully written by scan)
  //   tags     @104M    8 KB  (sentinels; exact-match poll -> poison-safe)
  //   xb 32 MB aliases ring; wb 1 MB aliases pscratch (both dead after gemm).
  unsigned short* xp = (unsigned short*)(ws);
  unsigned* ring     = (unsigned*)(ws + 67108864);
  float* pscratch    = (float*)(ws + 100663296);
  unsigned* tags     = (unsigned*)(ws + 109051904);
  unsigned short* xb = (unsigned short*)(ws + 67108864);
  unsigned short* wb = (unsigned short*)(ws + 100663296);

  cvt_kernel<<<8192, 256, 0, stream>>>(x, xb, 2097152);     // x fp32 -> bf16
  cvt_kernel<<<256, 256, 0, stream>>>(Wih, wb, 65536);      // W_ih fp32 -> bf16
  gemm_xp<<<2048, 256, 0, stream>>>(xb, wb, bih, bhh, xp);  // xp = x@W_ih^T + b
  hipMemsetAsync(ring, 0, 33554432, stream);                // tag-0 baseline
  scan_kernel<<<128, 256, 0, stream>>>(Whh, xp, Wfc, ring, tags, pscratch);
  head_reduce<<<8192, 256, 0, stream>>>(pscratch, bfc, out);
}